// Round 1
// baseline (319.686 us; speedup 1.0000x reference)
//
#include <hip/hip_runtime.h>

#define N_ENT 100000
#define DIM 512
#define RANK 256
#define HROWS 256
#define MAXOBS 32

typedef __attribute__((ext_vector_type(8))) short short8_t;
typedef __attribute__((ext_vector_type(4))) float f32x4;

__device__ __forceinline__ unsigned short f2bf(float f) {
  unsigned int x = __float_as_uint(f);
  x = x + 0x7fffu + ((x >> 16) & 1u);
  return (unsigned short)(x >> 16);
}

// ---- mask format handling (bool array storage dtype is harness-dependent) ----
// flags[r] = 1 if any nonzero byte at byte-index % 4 == r within first 8192 bytes.
// uint8 bool storage: nonzeros at many residues (prefix runs). int32: only r==0.
// float32 (1.0f): only r==2,3.
__device__ __forceinline__ int mask_mode(const int* flags) {
  int nz0 = flags[0], nz1 = flags[1], nz2 = flags[2], nz3 = flags[3];
  if (nz1 || (nz0 && (nz2 | nz3))) return 0;  // uint8
  if (nz0) return 1;                          // int32
  if (nz2 | nz3) return 2;                    // float32
  return 0;                                   // all-false: safe as uint8
}

__device__ __forceinline__ int mask_at(const void* mask, int idx, int mode) {
  if (mode == 0) return ((const unsigned char*)mask)[idx] != 0;
  if (mode == 1) return ((const int*)mask)[idx] != 0;
  return ((const float*)mask)[idx] != 0.0f;
}

__global__ void detect_mask_kernel(const unsigned char* __restrict__ mb, int* flags) {
  int t = threadIdx.x;  // 256 threads x 32 bytes = 8192 bytes (always in-bounds)
  int nz[4] = {0, 0, 0, 0};
  for (int j = 0; j < 32; ++j) {
    int idx = t * 32 + j;
    if (mb[idx]) nz[idx & 3] = 1;
  }
  for (int r = 0; r < 4; ++r)
    if (nz[r]) atomicOr(&flags[r], 1);
}

// ---- head extraction ----
__global__ void find_heads_kernel(const float* __restrict__ vec, int* counter, int* tmp) {
  int i = blockIdx.x * blockDim.x + threadIdx.x;
  if (i < N_ENT && vec[i] != 0.0f) {
    int p = atomicAdd(counter, 1);
    if (p < HROWS) tmp[p] = i;
  }
}

__global__ void sort_heads_kernel(const int* __restrict__ counter, const int* __restrict__ tmp,
                                  int* __restrict__ heads) {
  __shared__ int v[HROWS];
  int t = threadIdx.x;
  int cnt = *counter;
  if (cnt > HROWS) cnt = HROWS;
  v[t] = (t < cnt) ? tmp[t] : 0x7fffffff;
  __syncthreads();
  for (int k = 2; k <= HROWS; k <<= 1) {
    for (int j = k >> 1; j > 0; j >>= 1) {
      int ixj = t ^ j;
      if (ixj > t) {
        int a = v[t], b = v[ixj];
        bool up = ((t & k) == 0);
        if ((a > b) == up) { v[t] = b; v[ixj] = a; }
      }
      __syncthreads();
    }
  }
  heads[t] = (v[t] == 0x7fffffff) ? 0 : v[t];  // nonzero() pads with 0
}

// ---- query build: q[b][0:256]=re_h*re_r-im_h*im_r, q[b][256:512]=re_h*im_r+im_h*re_r ----
__global__ void build_q_kernel(const float* __restrict__ ent, const float* __restrict__ rel,
                               const int* __restrict__ heads, const int* __restrict__ rel_id,
                               unsigned short* __restrict__ q) {
  int b = blockIdx.x, k = threadIdx.x;
  int h = heads[b];
  const float* r = rel + (size_t)(*rel_id) * (2 * RANK);
  float re_h = ent[(size_t)h * DIM + k];
  float im_h = ent[(size_t)h * DIM + RANK + k];
  float re_r = r[k], im_r = r[RANK + k];
  q[(size_t)b * DIM + k]        = f2bf(re_h * re_r - im_h * im_r);
  q[(size_t)b * DIM + RANK + k] = f2bf(re_h * im_r + im_h * re_r);
}

// ---- score GEMM: scores = q(256x512) @ ent^T(512x100000), + per-row sum(exp) ----
// block: 256 thr (4 waves), 64-entity col tile; wave w owns rows [64w,64w+64).
__global__ __launch_bounds__(256) void gemm_scores_kernel(
    const float* __restrict__ ent, const unsigned short* __restrict__ q,
    float* __restrict__ scores, float* __restrict__ rowsum) {
  __shared__ unsigned short Bt[64][40];  // 64 ents x 32 k, +8 pad (bank spread)
  const int tid = threadIdx.x;
  const int lane = tid & 63;
  const int w = tid >> 6;
  const int e0 = blockIdx.x * 64;
  const int lrow = lane & 15;
  const int lk8 = (lane >> 4) * 8;

  f32x4 acc[4][4] = {};

  const int er = tid >> 2;       // staged entity row 0..63
  const int ko = (tid & 3) * 8;  // staged k offset
  const int ge = e0 + er;
  const bool gv = ge < N_ENT;
  const float* gp = ent + (size_t)(gv ? ge : 0) * DIM + ko;

  for (int kc = 0; kc < DIM; kc += 32) {
    float4 v0 = make_float4(0.f, 0.f, 0.f, 0.f), v1 = v0;
    if (gv) {
      v0 = *reinterpret_cast<const float4*>(gp + kc);
      v1 = *reinterpret_cast<const float4*>(gp + kc + 4);
    }
    unsigned short t8[8];
    t8[0] = f2bf(v0.x); t8[1] = f2bf(v0.y); t8[2] = f2bf(v0.z); t8[3] = f2bf(v0.w);
    t8[4] = f2bf(v1.x); t8[5] = f2bf(v1.y); t8[6] = f2bf(v1.z); t8[7] = f2bf(v1.w);
    *reinterpret_cast<short8_t*>(&Bt[er][ko]) = *reinterpret_cast<const short8_t*>(t8);
    __syncthreads();

    short8_t a[4], b[4];
#pragma unroll
    for (int fr = 0; fr < 4; ++fr) {
      const unsigned short* p = q + (size_t)(w * 64 + fr * 16 + lrow) * DIM + kc + lk8;
      a[fr] = *reinterpret_cast<const short8_t*>(p);
    }
#pragma unroll
    for (int fb = 0; fb < 4; ++fb)
      b[fb] = *reinterpret_cast<const short8_t*>(&Bt[fb * 16 + lrow][lk8]);
#pragma unroll
    for (int fr = 0; fr < 4; ++fr)
#pragma unroll
      for (int fb = 0; fb < 4; ++fb)
        acc[fr][fb] = __builtin_amdgcn_mfma_f32_16x16x32_bf16(a[fr], b[fb], acc[fr][fb], 0, 0, 0);
    __syncthreads();
  }

  // epilogue: C/D map col=lane&15, row=(lane>>4)*4+reg  [m89-verified]
#pragma unroll
  for (int fr = 0; fr < 4; ++fr) {
#pragma unroll
    for (int j = 0; j < 4; ++j) {
      const int row = w * 64 + fr * 16 + (lane >> 4) * 4 + j;
      float psum = 0.0f;
#pragma unroll
      for (int fb = 0; fb < 4; ++fb) {
        const int col = e0 + fb * 16 + lrow;
        if (col < N_ENT) {
          float s = acc[fr][fb][j];
          scores[(size_t)row * N_ENT + col] = s;
          psum += __expf(s);  // |s| small: no max-subtraction needed
        }
      }
      psum += __shfl_xor(psum, 1);
      psum += __shfl_xor(psum, 2);
      psum += __shfl_xor(psum, 4);
      psum += __shfl_xor(psum, 8);
      if (lrow == 0) atomicAdd(&rowsum[row], psum);
    }
  }
}

// ---- scaling: factor[i] = scaling_i / rowsum_i ----
__global__ void scaling_kernel(const float* __restrict__ scores, const float* __restrict__ rowsum,
                               const int* __restrict__ obs_idx, const void* __restrict__ mask,
                               const int* __restrict__ flags, float* __restrict__ factor) {
  int i = threadIdx.x;  // 256 head rows
  int mode = mask_mode(flags);
  float rs = rowsum[i];
  float sume = 0.0f;
  int cnt = 0;
  for (int j = 0; j < 32; ++j) {
    if (mask_at(mask, i * 32 + j, mode)) {
      int t = obs_idx[i * 32 + j];
      sume += __expf(scores[(size_t)i * N_ENT + t]);
      ++cnt;
    }
  }
  float scaling = 1.0f;
  if (cnt > 0) {
    float denom = fmaxf(sume / rs, 1e-30f);
    scaling = (float)cnt / denom;
  }
  factor[i] = scaling / rs;
}

// ---- finalize: out = clamp(threshold(exp(s)*factor)) in place ----
__global__ __launch_bounds__(256) void finalize_kernel(float* __restrict__ out,
                                                       const float* __restrict__ factor,
                                                       const int* __restrict__ train) {
  int row = blockIdx.y;
  int i4 = blockIdx.x * blockDim.x + threadIdx.x;
  if (i4 >= N_ENT / 4) return;
  float f = factor[row];
  float hi = (*train) ? (1.0f - 0.001f) : 1.0f;
  float4* p = reinterpret_cast<float4*>(out + (size_t)row * N_ENT) + i4;
  float4 v = *p;
  float vals[4] = {v.x, v.y, v.z, v.w};
#pragma unroll
  for (int j = 0; j < 4; ++j) {
    float s = __expf(vals[j]) * f;
    s = (s > 1e-4f) ? s : 0.0f;   // THRESHOLD
    vals[j] = fminf(s, hi);       // clip(0, hi); s >= 0 always
  }
  v.x = vals[0]; v.y = vals[1]; v.z = vals[2]; v.w = vals[3];
  *p = v;
}

// ---- observed positions -> 1.0 (train only) ----
__global__ void scatter_obs_kernel(float* __restrict__ out, const int* __restrict__ obs_idx,
                                   const void* __restrict__ mask, const int* __restrict__ flags,
                                   const int* __restrict__ train) {
  if (!(*train)) return;
  int t = blockIdx.x * blockDim.x + threadIdx.x;
  if (t >= HROWS * MAXOBS) return;
  int mode = mask_mode(flags);
  if (mask_at(mask, t, mode))
    out[(size_t)(t >> 5) * N_ENT + obs_idx[t]] = 1.0f;
}

extern "C" void kernel_launch(void* const* d_in, const int* in_sizes, int n_in,
                              void* d_out, int out_size, void* d_ws, size_t ws_size,
                              hipStream_t stream) {
  const float* ent      = (const float*)d_in[0];
  const float* rel      = (const float*)d_in[1];
  const float* head_vec = (const float*)d_in[2];
  const int* obs_idx    = (const int*)d_in[3];
  const void* obs_mask  = d_in[4];
  const int* rel_id     = (const int*)d_in[5];
  const int* train      = (const int*)d_in[7];
  float* out = (float*)d_out;

  char* ws = (char*)d_ws;
  int*   counter = (int*)(ws + 0);
  int*   flags   = (int*)(ws + 4);     // 4 ints
  float* rowsum  = (float*)(ws + 64);  // 256 f32
  float* factor  = (float*)(ws + 1088);// 256 f32
  int*   tmp     = (int*)(ws + 2112);  // 256 int
  int*   heads   = (int*)(ws + 3136);  // 256 int
  unsigned short* q = (unsigned short*)(ws + 4224);  // 256x512 bf16

  hipMemsetAsync(ws, 0, 2112, stream);  // counter + flags + rowsum (+factor pad)

  detect_mask_kernel<<<1, 256, 0, stream>>>((const unsigned char*)obs_mask, flags);
  find_heads_kernel<<<(N_ENT + 255) / 256, 256, 0, stream>>>(head_vec, counter, tmp);
  sort_heads_kernel<<<1, 256, 0, stream>>>(counter, tmp, heads);
  build_q_kernel<<<HROWS, 256, 0, stream>>>(ent, rel, heads, rel_id, q);
  gemm_scores_kernel<<<(N_ENT + 63) / 64, 256, 0, stream>>>(ent, q, out, rowsum);
  scaling_kernel<<<1, 256, 0, stream>>>(out, rowsum, obs_idx, obs_mask, flags, factor);
  finalize_kernel<<<dim3((N_ENT / 4 + 255) / 256, HROWS), 256, 0, stream>>>(out, factor, train);
  scatter_obs_kernel<<<(HROWS * MAXOBS + 255) / 256, 256, 0, stream>>>(out, obs_idx, obs_mask, flags, train);
}